// Round 1
// baseline (791.990 us; speedup 1.0000x reference)
//
#include <hip/hip_runtime.h>
#include <hip/hip_bf16.h>

// PGN fused kernel for MI355X.
// Shapes: B=4, N=512, H=128, MID=OUT=128, Z=2H=256.
// Strategy:
//   phaseA : s2[b,j,m]    = z@W_m2 + b_m2 + b_me          (fp32)
//            cst[b,i,m]   = z@W_m1 + b_m1 + msg_g[b,m]
//            front[b,i,m] = z@W_o1 + b_o1
//   mainK  : for each (b, i-tile of 32, j-chunk of 64):
//              partial[jc,b,i,m] = max over masked j of (s2[b,j,m] + edge[b,j,i]@W_me)
//            bf16 MFMA 16x16x32, edge staged fp32->bf16 through LDS (double buffered).
//   combine: agg = max over 8 partials (+cst, -1e6 if no neighbor);
//            out = relu(front + agg@W_o2 + b_o2)
// ws layout (floats): s2[262144] | cst[262144] | front[262144] | partial[8*262144]
//   total 11.5 MB.

#define BN 4
#define NN 512
#define HH 128
#define MIDD 128
#define ZD 256
#define JCN 8      // j-chunks
#define JPB 64     // j per block
#define TI 32      // i per block

typedef __attribute__((ext_vector_type(8))) short bf16x8;
typedef __attribute__((ext_vector_type(4))) float f32x4;

static __device__ __forceinline__ unsigned short f2bf(float f) {
  union { __hip_bfloat16 h; unsigned short u; } cv;
  cv.h = __float2bfloat16(f);
  return cv.u;
}
static __device__ __forceinline__ unsigned pack2(float a, float b) {
  return (unsigned)f2bf(a) | ((unsigned)f2bf(b) << 16);
}

// ---------------- Phase A: small fp32 GEMMs ----------------
__global__ __launch_bounds__(256) void phaseA(
    const float* __restrict__ node, const float* __restrict__ hidden,
    const float* __restrict__ graph,
    const float* __restrict__ Wm1, const float* __restrict__ bm1,
    const float* __restrict__ Wm2, const float* __restrict__ bm2,
    const float* __restrict__ bme,
    const float* __restrict__ Wmg, const float* __restrict__ bmg,
    const float* __restrict__ Wo1, const float* __restrict__ bo1,
    float* __restrict__ s2, float* __restrict__ cst, float* __restrict__ front)
{
  __shared__ float zsh[8][ZD];
  __shared__ float mg[MIDD];
  const int t = threadIdx.x;
  const int r0 = blockIdx.x * 8;          // 8 rows of (b*N+i), aligned within one b
  const int b = r0 / NN;

  #pragma unroll
  for (int s = 0; s < 8; ++s) {
    const int row = r0 + s;
    zsh[s][t] = (t < HH) ? node[(size_t)row * HH + t]
                         : hidden[(size_t)row * HH + (t - HH)];
  }
  if (t < MIDD) {
    float a = bmg[t];
    #pragma unroll 4
    for (int k = 0; k < HH; ++k) a += graph[b * HH + k] * Wmg[k * MIDD + t];
    mg[t] = a;
  }
  __syncthreads();

  const int c = t & 127;
  const int rh = t >> 7;                  // 0 -> rows 0..3, 1 -> rows 4..7
  float a2[4] = {0, 0, 0, 0}, a1[4] = {0, 0, 0, 0}, ao[4] = {0, 0, 0, 0};
  #pragma unroll 4
  for (int k = 0; k < ZD; ++k) {
    const float w2 = Wm2[k * MIDD + c];
    const float w1 = Wm1[k * MIDD + c];
    const float wo = Wo1[k * MIDD + c];
    #pragma unroll
    for (int q = 0; q < 4; ++q) {
      const float zv = zsh[rh * 4 + q][k];
      a2[q] += zv * w2; a1[q] += zv * w1; ao[q] += zv * wo;
    }
  }
  #pragma unroll
  for (int q = 0; q < 4; ++q) {
    const size_t row = r0 + rh * 4 + q;
    s2[row * MIDD + c]    = a2[q] + bm2[c] + bme[c];
    cst[row * MIDD + c]   = a1[q] + bm1[c] + mg[c];
    front[row * MIDD + c] = ao[q] + bo1[c];
  }
}

// ---------------- Main fused kernel ----------------
__global__ __launch_bounds__(256, 2) void mainK(
    const float* __restrict__ edge, const int* __restrict__ adj,
    const float* __restrict__ Wme, const float* __restrict__ s2,
    float* __restrict__ partial)
{
  __shared__ __align__(16) unsigned short ash[2][TI][HH + 8];  // +8 bf16 pad (row=272B)
  __shared__ unsigned bits[JPB];

  const int tid = threadIdx.x;
  const int wv = tid >> 6, lane = tid & 63;
  const int quad = lane >> 4, l15 = lane & 15;
  const int bx = blockIdx.x;
  const int it = bx & 15, jc = (bx >> 4) & 7, b = bx >> 7;
  const int i0 = it * TI, jb = jc * JPB;

  // B fragments of W_me (bf16), held in registers for the whole block lifetime.
  // B[k][n] layout for mfma_f32_16x16x32_bf16: n = lane&15, k = quad*8 + e.
  bf16x8 bf[2][4];
  #pragma unroll
  for (int sm = 0; sm < 2; ++sm) {
    #pragma unroll
    for (int ks = 0; ks < 4; ++ks) {
      union { bf16x8 v; unsigned short u[8]; } tmp;
      const int m = wv * 32 + sm * 16 + l15;
      #pragma unroll
      for (int e = 0; e < 8; ++e) {
        const int k = ks * 32 + quad * 8 + e;
        tmp.u[e] = f2bf(Wme[k * MIDD + m]);
      }
      bf[sm][ks] = tmp.v;
    }
  }

  // Adjacency bitmasks for this (b, i-tile, j-chunk): bits[jl] bit i' = adj[b][jb+jl][i0+i']
  for (int q = 0; q < 8; ++q) {
    const int jl = wv * 16 + q * 2 + (lane >> 5);
    const int i = i0 + (lane & 31);
    const int pred = adj[((size_t)(b * NN + jb + jl)) * NN + i] != 0;
    const unsigned long long m = __ballot(pred);
    if (lane == 0)  bits[jl] = (unsigned)m;
    if (lane == 32) bits[jl] = (unsigned)(m >> 32);
  }

  f32x4 acc[2][2];
  #pragma unroll
  for (int si = 0; si < 2; ++si)
    #pragma unroll
    for (int sm = 0; sm < 2; ++sm)
      acc[si][sm] = f32x4{-1e6f, -1e6f, -1e6f, -1e6f};

  float4 pf[4];
  // Prologue: stage j=0 tile into ash[0]
  {
    const float* p = edge + (((size_t)(b * NN + jb)) * NN + i0) * HH;
    #pragma unroll
    for (int s = 0; s < 4; ++s) pf[s] = *(const float4*)(p + s * 1024 + tid * 4);
    #pragma unroll
    for (int s = 0; s < 4; ++s) {
      const int e = s * 1024 + tid * 4;
      *(uint2*)&ash[0][e >> 7][e & 127] =
          make_uint2(pack2(pf[s].x, pf[s].y), pack2(pf[s].z, pf[s].w));
    }
  }

  const float* s2row = s2 + ((size_t)(b * NN + jb)) * MIDD;

  for (int jj = 0; jj < JPB; ++jj) {
    const int cur = jj & 1;
    __syncthreads();  // ash[cur] staged; previous reads of ash[cur^1] done

    // Prefetch next tile into registers (overlaps with MFMA below)
    if (jj + 1 < JPB) {
      const float* p = edge + (((size_t)(b * NN + jb + jj + 1)) * NN + i0) * HH;
      #pragma unroll
      for (int s = 0; s < 4; ++s) pf[s] = *(const float4*)(p + s * 1024 + tid * 4);
    }

    const unsigned mb = bits[jj];
    const float s2v0 = s2row[jj * MIDD + wv * 32 + l15];
    const float s2v1 = s2row[jj * MIDD + wv * 32 + 16 + l15];

    #pragma unroll
    for (int si = 0; si < 2; ++si) {
      bf16x8 af[4];
      #pragma unroll
      for (int ks = 0; ks < 4; ++ks)
        af[ks] = *(const bf16x8*)&ash[cur][si * 16 + l15][ks * 32 + quad * 8];
      #pragma unroll
      for (int sm = 0; sm < 2; ++sm) {
        f32x4 d = {0.f, 0.f, 0.f, 0.f};
        #pragma unroll
        for (int ks = 0; ks < 4; ++ks)
          d = __builtin_amdgcn_mfma_f32_16x16x32_bf16(af[ks], bf[sm][ks], d, 0, 0, 0);
        const float sv = sm ? s2v1 : s2v0;
        #pragma unroll
        for (int r = 0; r < 4; ++r) {
          const int ip = si * 16 + quad * 4 + r;     // i' within tile (D row)
          const float v = d[r] + sv;
          if ((mb >> ip) & 1u) acc[si][sm][r] = fmaxf(acc[si][sm][r], v);
        }
      }
    }

    // Convert + store prefetched tile into the other buffer
    if (jj + 1 < JPB) {
      #pragma unroll
      for (int s = 0; s < 4; ++s) {
        const int e = s * 1024 + tid * 4;
        *(uint2*)&ash[cur ^ 1][e >> 7][e & 127] =
            make_uint2(pack2(pf[s].x, pf[s].y), pack2(pf[s].z, pf[s].w));
      }
    }
  }

  // Epilogue: write per-chunk partial maxima
  float* pb = partial + ((size_t)jc * (BN * NN) + b * NN + i0) * MIDD;
  #pragma unroll
  for (int si = 0; si < 2; ++si)
    #pragma unroll
    for (int sm = 0; sm < 2; ++sm)
      #pragma unroll
      for (int r = 0; r < 4; ++r) {
        const int ip = si * 16 + quad * 4 + r;
        const int m = wv * 32 + sm * 16 + l15;
        pb[(size_t)ip * MIDD + m] = acc[si][sm][r];
      }
}

// ---------------- Combine: max over chunks + final GEMM + ReLU ----------------
__global__ __launch_bounds__(256) void combineK(
    const float* __restrict__ partial, const float* __restrict__ cst,
    const float* __restrict__ front, const float* __restrict__ Wo2,
    const float* __restrict__ bo2, float* __restrict__ out)
{
  __shared__ float agg[8][MIDD];
  const int t = threadIdx.x;
  const int c = t & 127, h = t >> 7;
  const int r0 = blockIdx.x * 8;

  for (int rr = h; rr < 8; rr += 2) {
    const size_t row = r0 + rr;
    float v = -1e6f;
    #pragma unroll
    for (int p = 0; p < JCN; ++p)
      v = fmaxf(v, partial[((size_t)p * (BN * NN) + row) * MIDD + c]);
    // all-masked column stays exactly -1e6 (matches reference); otherwise add const part
    agg[rr][c] = (v > -9.0e5f) ? (v + cst[row * MIDD + c]) : -1e6f;
  }
  __syncthreads();

  float a[4];
  #pragma unroll
  for (int q = 0; q < 4; ++q) {
    const size_t row = r0 + h * 4 + q;
    a[q] = front[row * MIDD + c] + bo2[c];
  }
  #pragma unroll 4
  for (int k = 0; k < MIDD; ++k) {
    const float w = Wo2[k * MIDD + c];
    #pragma unroll
    for (int q = 0; q < 4; ++q) a[q] += agg[h * 4 + q][k] * w;
  }
  #pragma unroll
  for (int q = 0; q < 4; ++q) {
    const size_t row = r0 + h * 4 + q;
    out[row * MIDD + c] = fmaxf(a[q], 0.f);
  }
}

extern "C" void kernel_launch(void* const* d_in, const int* in_sizes, int n_in,
                              void* d_out, int out_size, void* d_ws, size_t ws_size,
                              hipStream_t stream)
{
  const float* node   = (const float*)d_in[0];
  const float* edge   = (const float*)d_in[1];
  const float* graph  = (const float*)d_in[2];
  const int*   adj    = (const int*)d_in[3];
  const float* hidden = (const float*)d_in[4];
  const float* Wm1 = (const float*)d_in[5];
  const float* bm1 = (const float*)d_in[6];
  const float* Wm2 = (const float*)d_in[7];
  const float* bm2 = (const float*)d_in[8];
  const float* Wme = (const float*)d_in[9];
  const float* bme = (const float*)d_in[10];
  const float* Wmg = (const float*)d_in[11];
  const float* bmg = (const float*)d_in[12];
  const float* Wo1 = (const float*)d_in[13];
  const float* bo1 = (const float*)d_in[14];
  const float* Wo2 = (const float*)d_in[15];
  const float* bo2 = (const float*)d_in[16];

  float* ws      = (float*)d_ws;
  float* s2      = ws;                 // 262144
  float* cst     = ws + 262144;        // 262144
  float* front   = ws + 524288;        // 262144
  float* partial = ws + 786432;        // 8*262144 = 2097152
  float* out     = (float*)d_out;

  phaseA<<<256, 256, 0, stream>>>(node, hidden, graph, Wm1, bm1, Wm2, bm2, bme,
                                  Wmg, bmg, Wo1, bo1, s2, cst, front);
  mainK<<<512, 256, 0, stream>>>(edge, adj, Wme, s2, partial);
  combineK<<<256, 256, 0, stream>>>(partial, cst, front, Wo2, bo2, out);
}